// Round 1
// baseline (13557.968 us; speedup 1.0000x reference)
//
#include <hip/hip_runtime.h>
#include <hip/hip_bf16.h>
#include <stdint.h>

#define TT 1024
#define BB 512
#define II 128
#define HH 256
#define KX 129   // I + Z
#define KT 385   // I + Z + H
#define GG 1024  // 4H

__device__ __forceinline__ float fsig(float x) { return 1.0f / (1.0f + __expf(-x)); }
// exact algebraic identity: tanh(x) = 1 - 2/(exp(2x)+1); handles +-inf saturation correctly
__device__ __forceinline__ float ftanh(float x) { return 1.0f - 2.0f / (__expf(2.0f * x) + 1.0f); }

// Pack [W_ih | W_hh] into k-major bf16 WT[385][1024]; bias = b_ih + b_hh.
__global__ __launch_bounds__(256) void prep_kernel(
    const float* __restrict__ W_ih, const float* __restrict__ W_hh,
    const float* __restrict__ b_ih, const float* __restrict__ b_hh,
    uint16_t* __restrict__ WT, float* __restrict__ bias)
{
    int e = blockIdx.x * blockDim.x + threadIdx.x;
    if (e < KT * GG) {
        int k = e / GG, j = e - k * GG;
        float w = (k < KX) ? W_ih[j * KX + k] : W_hh[j * HH + (k - KX)];
        WT[e] = __bfloat16_as_ushort(__float2bfloat16(w));
    }
    if (e < GG) bias[e] = b_ih[e] + b_hh[e];
}

__global__ __launch_bounds__(512) void lstm_kernel(
    const float* __restrict__ x,      // [T][B][I]
    const float* __restrict__ h0, const float* __restrict__ c0,
    const float* __restrict__ z0,
    const uint32_t* __restrict__ WT2, // [385][512] bf16x2 packed
    const float* __restrict__ bias,   // [1024]
    const float* __restrict__ Wfc,    // [256]
    const float* __restrict__ bfc,    // [1]
    float* __restrict__ out)          // [T*B] ++ [B*H] ++ [B*H]
{
    __shared__ float axz[2][132];     // x (0..127), z at [128]
    __shared__ float hL[2][HH];
    __shared__ float cL[2][HH];
    __shared__ float gates[2][GG];
    __shared__ float red[2][4];

    const int tid = threadIdx.x;
    const int b0 = blockIdx.x * 2;
    const int pr = tid >> 7, pi = tid & 127;

    // init persistent per-block state
    if (tid < HH) {
        hL[0][tid] = h0[b0 * HH + tid];
        hL[1][tid] = h0[(b0 + 1) * HH + tid];
        cL[0][tid] = c0[b0 * HH + tid];
        cL[1][tid] = c0[(b0 + 1) * HH + tid];
    }
    if (tid < 2) axz[tid][II] = z0[b0 + tid];
    if (tid < 256) axz[pr][pi] = x[(b0 + pr) * II + pi];  // stage x_0

    // per-thread loop-invariant constants
    const float2 bj = *(const float2*)&bias[tid * 2];
    const float wfc = (tid < HH) ? Wfc[tid] : 0.0f;
    const float bfcs = bfc[0];

    for (int t = 0; t < TT; ++t) {
        __syncthreads();  // A: x_t, z_t, h_t visible

        // prefetch x_{t+1} (latency hidden under gate loop; consumed after sync B)
        float xnext = 0.0f;
        if (tid < 256 && t + 1 < TT)
            xnext = x[(size_t)(t + 1) * (BB * II) + (b0 + pr) * II + pi];

        // gates for cols j0=2*tid, j0+1; rows b0, b0+1
        float a00 = bj.x, a01 = bj.x, a10 = bj.y, a11 = bj.y;
        #pragma unroll 8
        for (int k = 0; k < KX; ++k) {
            uint32_t w2 = WT2[k * 512 + tid];
            float wlo = __uint_as_float(w2 << 16);
            float whi = __uint_as_float(w2 & 0xffff0000u);
            float v0 = axz[0][k], v1 = axz[1][k];
            a00 = fmaf(wlo, v0, a00);
            a01 = fmaf(wlo, v1, a01);
            a10 = fmaf(whi, v0, a10);
            a11 = fmaf(whi, v1, a11);
        }
        #pragma unroll 8
        for (int u = 0; u < HH; ++u) {
            uint32_t w2 = WT2[(KX + u) * 512 + tid];
            float wlo = __uint_as_float(w2 << 16);
            float whi = __uint_as_float(w2 & 0xffff0000u);
            float v0 = hL[0][u], v1 = hL[1][u];
            a00 = fmaf(wlo, v0, a00);
            a01 = fmaf(wlo, v1, a01);
            a10 = fmaf(whi, v0, a10);
            a11 = fmaf(whi, v1, a11);
        }
        *(float2*)&gates[0][tid * 2] = make_float2(a00, a10);
        *(float2*)&gates[1][tid * 2] = make_float2(a01, a11);
        __syncthreads();  // B: gates ready; all reads of axz/hL done

        if (tid < 256) {
            axz[pr][pi] = xnext;  // stage x_{t+1} (safe after B)
            float pz0, pz1;
            {   // row 0, u = tid
                float ig = fsig(gates[0][tid]);
                float fg = fsig(gates[0][256 + tid]);
                float g2 = ftanh(gates[0][512 + tid]);
                float og = fsig(gates[0][768 + tid]);
                float c = fg * cL[0][tid] + ig * g2;
                float h = og * ftanh(c);
                cL[0][tid] = c; hL[0][tid] = h;
                pz0 = h * wfc;
            }
            {   // row 1
                float ig = fsig(gates[1][tid]);
                float fg = fsig(gates[1][256 + tid]);
                float g2 = ftanh(gates[1][512 + tid]);
                float og = fsig(gates[1][768 + tid]);
                float c = fg * cL[1][tid] + ig * g2;
                float h = og * ftanh(c);
                cL[1][tid] = c; hL[1][tid] = h;
                pz1 = h * wfc;
            }
            // z = tanh(h @ Wfc^T + bfc): reduce 256 products (waves 0..3)
            #pragma unroll
            for (int off = 32; off >= 1; off >>= 1) {
                pz0 += __shfl_down(pz0, off, 64);
                pz1 += __shfl_down(pz1, off, 64);
            }
            if ((tid & 63) == 0) {
                red[0][tid >> 6] = pz0;
                red[1][tid >> 6] = pz1;
            }
        }
        __syncthreads();  // C: wave partials ready
        if (tid < 2) {
            float s = red[tid][0] + red[tid][1] + red[tid][2] + red[tid][3];
            float z = ftanh(s + bfcs);
            axz[tid][II] = z;                       // feeds step t+1
            out[(size_t)t * BB + b0 + tid] = z;     // outputs[t][b]
        }
    }

    __syncthreads();
    if (tid < HH) {
        out[TT * BB + b0 * HH + tid] = hL[0][tid];
        out[TT * BB + (b0 + 1) * HH + tid] = hL[1][tid];
        out[TT * BB + BB * HH + b0 * HH + tid] = cL[0][tid];
        out[TT * BB + BB * HH + (b0 + 1) * HH + tid] = cL[1][tid];
    }
}

extern "C" void kernel_launch(void* const* d_in, const int* in_sizes, int n_in,
                              void* d_out, int out_size, void* d_ws, size_t ws_size,
                              hipStream_t stream) {
    const float* x    = (const float*)d_in[0];
    const float* h0   = (const float*)d_in[1];
    const float* c0   = (const float*)d_in[2];
    const float* z0   = (const float*)d_in[3];
    const float* W_ih = (const float*)d_in[4];
    const float* W_hh = (const float*)d_in[5];
    const float* b_ih = (const float*)d_in[6];
    const float* b_hh = (const float*)d_in[7];
    const float* Wfc  = (const float*)d_in[8];
    const float* bfc  = (const float*)d_in[9];
    float* out = (float*)d_out;

    uint16_t* WT = (uint16_t*)d_ws;                                   // 788,480 B
    float* bias  = (float*)((char*)d_ws + (size_t)KT * GG * 2);       // 4,096 B

    int prep_total = KT * GG;
    prep_kernel<<<(prep_total + 255) / 256, 256, 0, stream>>>(W_ih, W_hh, b_ih, b_hh, WT, bias);
    lstm_kernel<<<BB / 2, 512, 0, stream>>>(x, h0, c0, z0, (const uint32_t*)WT, bias, Wfc, bfc, out);
}